// Round 1
// baseline (350.649 us; speedup 1.0000x reference)
//
#include <hip/hip_runtime.h>

typedef unsigned short u16;
typedef unsigned int u32;
typedef __bf16 bf16x8 __attribute__((ext_vector_type(8)));
typedef float f32x4 __attribute__((ext_vector_type(4)));

// ---------- helpers ----------

__device__ __forceinline__ u16 f2bf(float f) {  // round-to-nearest-even fp32->bf16
  u32 u = __builtin_bit_cast(u32, f);
  u32 r = (u + 0x7fffu + ((u >> 16) & 1u)) >> 16;
  return (u16)r;
}
__device__ __forceinline__ u32 pk2(float a, float b) {
  return (u32)f2bf(a) | ((u32)f2bf(b) << 16);
}
__device__ __forceinline__ f32x4 mfma16(bf16x8 a, bf16x8 b, f32x4 c) {
  return __builtin_amdgcn_mfma_f32_16x16x32_bf16(a, b, c, 0, 0, 0);
}
// async global->LDS, 16B/lane; LDS dest = wave-uniform base + lane*16
__device__ __forceinline__ void glds16(const void* g, void* l) {
  typedef __attribute__((address_space(1))) void as1_void;
  typedef __attribute__((address_space(3))) void as3_void;
  __builtin_amdgcn_global_load_lds((as1_void*)g, (as3_void*)l, 16, 0, 0);
}

// ---------- kernel 1: x fp32 -> bf16 ----------

__launch_bounds__(256)
__global__ void convert_x_k(const float* __restrict__ in, u16* __restrict__ out) {
  long i = ((long)blockIdx.x * 256 + threadIdx.x) * 8;
  float4 f0 = *(const float4*)(in + i);
  float4 f1 = *(const float4*)(in + i + 4);
  uint4 o;
  o.x = pk2(f0.x, f0.y);
  o.y = pk2(f0.z, f0.w);
  o.z = pk2(f1.x, f1.y);
  o.w = pk2(f1.z, f1.w);
  *(uint4*)(out + i) = o;
}

// ---------- kernel 2: W [K][N] fp32 -> Wt [N][K] bf16 ----------

__launch_bounds__(256)
__global__ void transpose_w_k(const float* __restrict__ in, u16* __restrict__ out,
                              int K, int N) {
  __shared__ float t[32][33];
  int n0 = blockIdx.x * 32, k0 = blockIdx.y * 32;
  int tx = threadIdx.x & 31, ty = threadIdx.x >> 5;  // 8 rows per pass
#pragma unroll
  for (int s = 0; s < 32; s += 8)
    t[ty + s][tx] = in[(long)(k0 + ty + s) * N + n0 + tx];
  __syncthreads();
#pragma unroll
  for (int s = 0; s < 32; s += 8)
    out[(long)(n0 + ty + s) * K + k0 + tx] = f2bf(t[tx][ty + s]);
}

// ---------- kernel 3/5: C = A(bf16 [M][K]) * Bt(bf16 [N][K])^T + bias ----------
// 128x128 tile, BK=64, 4 waves, 4x4 MFMA 16x16x32 tiles per wave.
// LDS chunk-major [c][row][32]: conflict-free ds_read_b128 frag reads.
// EPI=0: scatter to q/k windowed [b][h][nw][w][d] and v transposed [b][h][nw][d][w] (bf16)
// EPI=1: fp32 row-major output (d_out)

template <int EPI>
__launch_bounds__(256)
__global__ void gemm_bt(const u16* __restrict__ A, const u16* __restrict__ Bt,
                        const float* __restrict__ bias, int K, int N,
                        u16* __restrict__ oq, u16* __restrict__ okk,
                        u16* __restrict__ ov, float* __restrict__ ofp) {
  __shared__ u16 Asm[8192];  // idx = c*4096 + row*32 + t   (c = k-chunk of 32)
  __shared__ u16 Bsm[8192];

  const int tid = threadIdx.x;
  const int wave = tid >> 6, lane = tid & 63;
  const int quad = lane >> 4, l15 = lane & 15;
  const int wm = wave >> 1, wn = wave & 1;
  const long arow0 = (long)blockIdx.y * 128;
  const long brow0 = (long)blockIdx.x * 128;

  f32x4 acc[4][4] = {};

  for (int k0 = 0; k0 < K; k0 += 64) {
#pragma unroll
    for (int rd = 0; rd < 4; ++rd) {
      int flat = rd * 256 + tid;               // 0..1023 groups of 8 elems
      int c = flat >> 9, row = (flat >> 2) & 127, g = flat & 3;
      const long koff = k0 + c * 32 + g * 8;
      glds16(A + (arow0 + row) * K + koff, &Asm[(rd * 256 + wave * 64) * 8]);
      glds16(Bt + (brow0 + row) * K + koff, &Bsm[(rd * 256 + wave * 64) * 8]);
    }
    __syncthreads();
#pragma unroll
    for (int c = 0; c < 2; ++c) {
      bf16x8 af[4], bfr[4];
#pragma unroll
      for (int i = 0; i < 4; ++i)
        af[i] = *(const bf16x8*)&Asm[c * 4096 + (wm * 64 + i * 16 + l15) * 32 + quad * 8];
#pragma unroll
      for (int j = 0; j < 4; ++j)
        bfr[j] = *(const bf16x8*)&Bsm[c * 4096 + (wn * 64 + j * 16 + l15) * 32 + quad * 8];
#pragma unroll
      for (int i = 0; i < 4; ++i)
#pragma unroll
        for (int j = 0; j < 4; ++j)
          acc[i][j] = mfma16(af[i], bfr[j], acc[i][j]);
    }
    __syncthreads();
  }

  // epilogue: D-layout row = quad*4 + r, col = l15 (within each 16x16 tile)
#pragma unroll
  for (int i = 0; i < 4; ++i) {
    const int Rb = (int)arow0 + wm * 64 + i * 16 + quad * 4;
#pragma unroll
    for (int j = 0; j < 4; ++j) {
      const int C = (int)brow0 + wn * 64 + j * 16 + l15;
      const float bc = bias[C];
#pragma unroll
      for (int r = 0; r < 4; ++r) {
        const float val = acc[i][j][r] + bc;
        const int R = Rb + r;
        if constexpr (EPI == 0) {
          const int which = C >> 9, cin = C & 511;
          const int hc = cin >> 6, dc = cin & 63;
          const int b = R >> 13, nn = R & 8191;
          const int nw = nn >> 8, w = nn & 255;
          const long base = (long)((b * 8 + hc) * 32 + nw);
          const u16 bv = f2bf(val);
          if (which == 0)      oq[(base * 256 + w) * 64 + dc] = bv;
          else if (which == 1) okk[(base * 256 + w) * 64 + dc] = bv;
          else                 ov[(base * 64 + dc) * 256 + w] = bv;   // v transposed [d][w]
        } else {
          ofp[(long)R * N + C] = val;
        }
      }
    }
  }
}

// ---------- kernel 4: block-local attention, one block per (b,h,window) ----------
// q,k windowed [w=256][d=64] bf16; v pre-transposed [d=64][w=256] bf16.
// Per wave: 4 sub-chunks of 16 q-rows, wave-local softmax (shfl width 16),
// P routed through per-wave LDS (C/D-layout -> A-layout transform).

__launch_bounds__(256)
__global__ void attn_win(const u16* __restrict__ qg, const u16* __restrict__ kg,
                         const u16* __restrict__ vtg, const float* __restrict__ bias,
                         u16* __restrict__ og) {
  __shared__ u16 vT[8 * 2048];  // chunk-major: [kk][d][t], v[kk*32+t][d]   (32 KB)
  __shared__ u16 P[4 * 4096];   // per-wave [kk][i][t] = P[i][kk*32+t]      (32 KB)

  const int tid = threadIdx.x;
  const int wave = tid >> 6, lane = tid & 63;
  const int quad = lane >> 4, l15 = lane & 15;

  const int wi = blockIdx.x;
  const int nwi = wi & 31, hi = (wi >> 5) & 7, bi = wi >> 8;
  const long winoff = (long)((bi * 8 + hi) * 32 + nwi) * 16384;
  const u16* qw = qg + winoff;
  const u16* kw = kg + winoff;
  const u16* vw = vtg + winoff;                 // [d][256]
  const float* bh = bias + (long)hi * 65536;    // [256][256]

  // stage v^T into chunk-major LDS
#pragma unroll
  for (int it = 0; it < 8; ++it) {
    int flat = it * 256 + tid;                  // 0..2047 groups of 8 tokens
    int d = flat >> 5, grp = flat & 31;
    int4 val = *(const int4*)&vw[d * 256 + grp * 8];
    *(int4*)&vT[(grp >> 2) * 2048 + d * 32 + (grp & 3) * 8] = val;
  }
  __syncthreads();

  u16* Pw = &P[wave * 4096];
  const float scale = 0.125f;  // 64^-0.5

  for (int sc = 0; sc < 4; ++sc) {
    const int q0 = wave * 64 + sc * 16;  // window-row base of this 16-row sub-chunk

    // S = q k^T : A-frags (q) and B-frags (k) straight from global (L1/L2-hot)
    bf16x8 aq0 = *(const bf16x8*)&qw[(q0 + l15) * 64 + quad * 8];
    bf16x8 aq1 = *(const bf16x8*)&qw[(q0 + l15) * 64 + 32 + quad * 8];

    f32x4 s[16];
#pragma unroll
    for (int jt = 0; jt < 16; ++jt) {
      bf16x8 b0 = *(const bf16x8*)&kw[(jt * 16 + l15) * 64 + quad * 8];
      bf16x8 b1 = *(const bf16x8*)&kw[(jt * 16 + l15) * 64 + 32 + quad * 8];
      f32x4 z = {0.f, 0.f, 0.f, 0.f};
      z = mfma16(aq0, b0, z);
      z = mfma16(aq1, b1, z);
      s[jt] = z;
    }

    // scale + bias (D-layout: row = q0+quad*4+r, col = jt*16+l15)
#pragma unroll
    for (int jt = 0; jt < 16; ++jt)
#pragma unroll
      for (int r = 0; r < 4; ++r)
        s[jt][r] = s[jt][r] * scale + bh[(q0 + quad * 4 + r) * 256 + jt * 16 + l15];

    // wave-local softmax: row lives in this quad's 16 lanes x 16 regs
    float inv[4];
#pragma unroll
    for (int r = 0; r < 4; ++r) {
      float m = s[0][r];
#pragma unroll
      for (int jt = 1; jt < 16; ++jt) m = fmaxf(m, s[jt][r]);
#pragma unroll
      for (int off = 1; off < 16; off <<= 1) m = fmaxf(m, __shfl_xor(m, off, 16));
      float sum = 0.f;
#pragma unroll
      for (int jt = 0; jt < 16; ++jt) {
        float p = __expf(s[jt][r] - m);
        s[jt][r] = p;
        sum += p;
      }
#pragma unroll
      for (int off = 1; off < 16; off <<= 1) sum += __shfl_xor(sum, off, 16);
      inv[r] = 1.0f / sum;
    }

    // P -> LDS (chunk-major), C/D-layout -> A-layout transform
#pragma unroll
    for (int jt = 0; jt < 16; ++jt)
#pragma unroll
      for (int r = 0; r < 4; ++r)
        Pw[(jt >> 1) * 512 + (quad * 4 + r) * 32 + (jt & 1) * 16 + l15] = f2bf(s[jt][r]);

    // O = P v : K=256 over 8 k-steps
    f32x4 o[4] = {};
#pragma unroll
    for (int kk = 0; kk < 8; ++kk) {
      bf16x8 ap = *(const bf16x8*)&Pw[kk * 512 + l15 * 32 + quad * 8];
#pragma unroll
      for (int dt = 0; dt < 4; ++dt) {
        bf16x8 bv = *(const bf16x8*)&vT[kk * 2048 + (dt * 16 + l15) * 32 + quad * 8];
        o[dt] = mfma16(ap, bv, o[dt]);
      }
    }

    // epilogue: divide by rowsum (same lane holds matching rows), store [b][n][h*64+d]
    const long rowbase = ((long)bi * 8192 + nwi * 256 + q0 + quad * 4) * 512 + hi * 64;
#pragma unroll
    for (int dt = 0; dt < 4; ++dt)
#pragma unroll
      for (int r = 0; r < 4; ++r)
        og[rowbase + (long)r * 512 + dt * 16 + l15] = f2bf(o[dt][r] * inv[r]);
  }
}

// ---------- launcher ----------

extern "C" void kernel_launch(void* const* d_in, const int* in_sizes, int n_in,
                              void* d_out, int out_size, void* d_ws, size_t ws_size,
                              hipStream_t stream) {
  const float* x     = (const float*)d_in[0];
  const float* Wqkv  = (const float*)d_in[1];
  const float* bqkv  = (const float*)d_in[2];
  const float* Wproj = (const float*)d_in[3];
  const float* bproj = (const float*)d_in[4];
  const float* abias = (const float*)d_in[5];
  float* out = (float*)d_out;

  // workspace layout (bytes):
  //   q: 32Mi*2=33,554,432 | k: +33,554,432 | v: +33,554,432
  //   WqkvT bf16: 1,572,864 | WprojT bf16: 524,288
  //   x_bf16 (aliased as attn_out after qkv GEMM consumes it): 33,554,432
  char* ws = (char*)d_ws;
  u16* qws    = (u16*)(ws);
  u16* kws    = (u16*)(ws + 33554432L);
  u16* vws    = (u16*)(ws + 67108864L);
  u16* wqkvT  = (u16*)(ws + 100663296L);
  u16* wprojT = (u16*)(ws + 102236160L);
  u16* xbf    = (u16*)(ws + 102760448L);
  u16* attnout = xbf;  // safe: x_bf16 dead after qkv GEMM (stream-ordered)

  convert_x_k<<<8192, 256, 0, stream>>>(x, xbf);                       // 4*8192*512 elems
  transpose_w_k<<<dim3(48, 16), 256, 0, stream>>>(Wqkv, wqkvT, 512, 1536);
  transpose_w_k<<<dim3(16, 16), 256, 0, stream>>>(Wproj, wprojT, 512, 512);
  gemm_bt<0><<<dim3(12, 256), 256, 0, stream>>>(xbf, wqkvT, bqkv, 512, 1536,
                                                qws, kws, vws, nullptr);
  attn_win<<<1024, 256, 0, stream>>>(qws, kws, vws, abias, attnout);
  gemm_bt<1><<<dim3(4, 256), 256, 0, stream>>>(attnout, wprojT, bproj, 512, 512,
                                               nullptr, nullptr, nullptr, out);
}